// Round 18
// baseline (156.880 us; speedup 1.0000x reference)
//
#include <hip/hip_runtime.h>
#include <hip/hip_fp16.h>

#define NEG_SLOPE 0.01f
#define RANGE_BITS 15
#define RANGE (1 << RANGE_BITS)     // 32768 nodes per histogram range (16-bit counters, 64 KB LDS)
#define HWORDS (RANGE / 2)          // 16384 packed uint32 words
#define SLICE_BITS 16
#define SLICE (1 << SLICE_BITS)     // 65536 edges per slice (measured-best)
#define PSTRIDE 64                  // halfs per p/q row (128 B = exactly one cache line)

typedef _Float16 f16x8 __attribute__((ext_vector_type(8)));
typedef float f32x4 __attribute__((ext_vector_type(4)));

__device__ __forceinline__ float lrelu(float x) { return x > 0.f ? x : NEG_SLOPE * x; }

__device__ __forceinline__ unsigned pack2h(float a, float b) {
    __half2 h = __floats2half2_rn(a, b);
    unsigned u; __builtin_memcpy(&u, &h, 4); return u;
}
__device__ __forceinline__ float2 unpack2(unsigned u) {
    __half2 h = *reinterpret_cast<__half2*>(&u);
    return __half22float2(h);
}
__device__ __forceinline__ f16x8 u4h8(uint4 u) {
    f16x8 r; __builtin_memcpy(&r, &u, 16); return r;
}

// ---------------- FUSED pass A: count blocks [0,NB_CNT) + mlp blocks [NB_CNT, NB_CNT+NB_MLP4)
// count: per-(array,range,slice) LDS histogram (16-bit counters, int4 scan)
// mlp:   1024 threads = 4 sub-tiles x 64 rows; p_u = lrelu(lrelu(X@W1+b1)@W2+b2)@W3 (UNSCALED)
__global__ __launch_bounds__(1024) void countmlp_kernel(
    const int* __restrict__ snd, const int* __restrict__ rcv,
    unsigned* __restrict__ partial, unsigned short* __restrict__ pos16,
    int nE, int NR, int NS, int NB_CNT,
    const float* __restrict__ X, const float* __restrict__ W1, const float* __restrict__ b1,
    const float* __restrict__ W2, const float* __restrict__ b2, const float* __restrict__ W3,
    __half* __restrict__ p, int nN)
{
    __shared__ unsigned shraw[16384];   // 64 KB: count hist OR mlp {R1 16KB | R2 4x8KB}
    const int blk = (int)blockIdx.x;

    if (blk < NB_CNT) {
        // ===================== COUNT path =====================
        unsigned* hist = shraw;
        const int b = blk;
        const int a = b / (NR * NS);
        const int rem = b - a * NR * NS;
        const int r = rem / NS;
        const int s = rem - r * NS;
        const int t = threadIdx.x;
        for (int k = t; k < HWORDS; k += 1024) hist[k] = 0u;
        __syncthreads();
        const int base = r << RANGE_BITS;
        const int lo = s << SLICE_BITS;
        const int hi = min(lo + SLICE, nE);
        const int n4 = (hi - lo) >> 2;
        const int* arr = (a == 0) ? rcv : snd;
        const int4* arr4 = (const int4*)(arr + lo);
        if (a == 0) {
            for (int i4 = t; i4 < n4; i4 += 1024) {
                const int4 v = arr4[i4];
                const int ib = lo + i4 * 4;
                int vv[4] = {v.x, v.y, v.z, v.w};
#pragma unroll
                for (int c = 0; c < 4; ++c) {
                    const unsigned d = (unsigned)(vv[c] - base);
                    if (d < (unsigned)RANGE) {
                        const unsigned sh = (d & 1u) << 4;
                        const unsigned old = atomicAdd(&hist[d >> 1], 1u << sh);
                        pos16[ib + c] = (unsigned short)((old >> sh) & 0xffffu);
                    }
                }
            }
            for (int i = lo + n4 * 4 + t; i < hi; i += 1024) {
                const unsigned d = (unsigned)(arr[i] - base);
                if (d < (unsigned)RANGE) {
                    const unsigned sh = (d & 1u) << 4;
                    const unsigned old = atomicAdd(&hist[d >> 1], 1u << sh);
                    pos16[i] = (unsigned short)((old >> sh) & 0xffffu);
                }
            }
        } else {
            for (int i4 = t; i4 < n4; i4 += 1024) {
                const int4 v = arr4[i4];
                int vv[4] = {v.x, v.y, v.z, v.w};
#pragma unroll
                for (int c = 0; c < 4; ++c) {
                    const unsigned d = (unsigned)(vv[c] - base);
                    if (d < (unsigned)RANGE) atomicAdd(&hist[d >> 1], 1u << ((d & 1u) << 4));
                }
            }
            for (int i = lo + n4 * 4 + t; i < hi; i += 1024) {
                const unsigned d = (unsigned)(arr[i] - base);
                if (d < (unsigned)RANGE) atomicAdd(&hist[d >> 1], 1u << ((d & 1u) << 4));
            }
        }
        __syncthreads();
        unsigned* dst = partial + (size_t)((a * NR + r) * NS + s) * HWORDS;
        for (int k = t; k < HWORDS; k += 1024) dst[k] = hist[k];
    } else {
        // ===================== MLP path (4 sub-tiles x 64 rows) =====================
        uint4* R1 = (uint4*)shraw;                    // 1024 uint4 (16 KB) shared weights
        const int t10 = (int)threadIdx.x;
        const int sub = t10 >> 8;                     // 0..3
        const int t   = t10 & 255;                    // within sub-tile
        const int w   = t >> 6;
        const int l   = t & 63;
        const int lrow = l & 15;
        const int lq   = l >> 4;
        const int row0 = (blk - NB_CNT) * 256 + sub * 64;
        uint4* R2 = (uint4*)shraw + 1024 + sub * 512; // 512 uint4 (8 KB) per sub-tile

        // stage W1T (sub 0 only)
        if (sub == 0) {
            const int c = l;
            for (int ch = 0; ch < 4; ++ch) {
                const int kc = 4 * w + ch;
                const float* wp = W1 + (kc * 8) * 64 + c;
                uint4 u;
                u.x = pack2h(wp[0],       wp[64]);
                u.y = pack2h(wp[2 * 64],  wp[3 * 64]);
                u.z = pack2h(wp[4 * 64],  wp[5 * 64]);
                u.w = pack2h(wp[6 * 64],  wp[7 * 64]);
                R1[c * 16 + (kc ^ (c & 7))] = u;
            }
        }

        const int grow = row0 + 16 * w + lrow;
        const bool rowok = grow < nN;
        const float* xr = X + (size_t)grow * 128 + lq * 8;

        float4 xa[4], xb[4];
#pragma unroll
        for (int ks = 0; ks < 4; ++ks) {
            xa[ks] = make_float4(0.f, 0.f, 0.f, 0.f);
            xb[ks] = xa[ks];
            if (rowok) {
                xa[ks] = *(const float4*)(xr + 32 * ks);
                xb[ks] = *(const float4*)(xr + 32 * ks + 4);
            }
        }
        __syncthreads();

        f32x4 acc1[4];
#pragma unroll
        for (int nt = 0; nt < 4; ++nt) acc1[nt] = (f32x4){0.f, 0.f, 0.f, 0.f};

#pragma unroll
        for (int ks = 0; ks < 4; ++ks) {
            uint4 au;
            au.x = pack2h(xa[ks].x, xa[ks].y); au.y = pack2h(xa[ks].z, xa[ks].w);
            au.z = pack2h(xb[ks].x, xb[ks].y); au.w = pack2h(xb[ks].z, xb[ks].w);
            const f16x8 af = u4h8(au);
            const int kc = 4 * ks + lq;
#pragma unroll
            for (int nt = 0; nt < 4; ++nt) {
                const int c = 16 * nt + lrow;
                const uint4 bu = R1[c * 16 + (kc ^ (c & 7))];
                acc1[nt] = __builtin_amdgcn_mfma_f32_16x16x32_f16(af, u4h8(bu), acc1[nt], 0, 0, 0);
            }
        }
        __syncthreads();

        {
            __half* hh = (__half*)R2;
#pragma unroll
            for (int nt = 0; nt < 4; ++nt) {
                const int col = 16 * nt + lrow;
                const float bv = b1[col];
                const int ch = col >> 3, cl = col & 7;
#pragma unroll
                for (int r = 0; r < 4; ++r) {
                    const int rw = 16 * w + 4 * lq + r;
                    hh[rw * 64 + ((ch ^ (rw & 7)) * 8) + cl] = __float2half(lrelu(acc1[nt][r] + bv));
                }
            }
            if (sub == 0) {
                const int c = l;
#pragma unroll
                for (int ch = 0; ch < 2; ++ch) {
                    const int kc = 2 * w + ch;
                    const float* wp = W2 + (kc * 8) * 64 + c;
                    uint4 u;
                    u.x = pack2h(wp[0],      wp[64]);
                    u.y = pack2h(wp[2 * 64], wp[3 * 64]);
                    u.z = pack2h(wp[4 * 64], wp[5 * 64]);
                    u.w = pack2h(wp[6 * 64], wp[7 * 64]);
                    R1[c * 8 + (kc ^ (c & 7))] = u;
                }
                if (c < 48) {
                    const bool cv = c < 40;
#pragma unroll
                    for (int ch = 0; ch < 2; ++ch) {
                        const int kc = 2 * w + ch;
                        const float* wp = W3 + (kc * 8) * 40 + c;
                        uint4 u;
                        u.x = pack2h(cv ? wp[0]      : 0.f, cv ? wp[40]     : 0.f);
                        u.y = pack2h(cv ? wp[2 * 40] : 0.f, cv ? wp[3 * 40] : 0.f);
                        u.z = pack2h(cv ? wp[4 * 40] : 0.f, cv ? wp[5 * 40] : 0.f);
                        u.w = pack2h(cv ? wp[6 * 40] : 0.f, cv ? wp[7 * 40] : 0.f);
                        R1[512 + c * 8 + (kc ^ (c & 7))] = u;
                    }
                }
            }
        }
        __syncthreads();

        f32x4 acc2[4];
#pragma unroll
        for (int nt = 0; nt < 4; ++nt) acc2[nt] = (f32x4){0.f, 0.f, 0.f, 0.f};
        {
            const int ar = 16 * w + lrow;
#pragma unroll
            for (int ks = 0; ks < 2; ++ks) {
                const int kc = 4 * ks + lq;
                const f16x8 af = u4h8(R2[ar * 8 + (kc ^ (ar & 7))]);
#pragma unroll
                for (int nt = 0; nt < 4; ++nt) {
                    const int c = 16 * nt + lrow;
                    const uint4 bu = R1[c * 8 + (kc ^ (c & 7))];
                    acc2[nt] = __builtin_amdgcn_mfma_f32_16x16x32_f16(af, u4h8(bu), acc2[nt], 0, 0, 0);
                }
            }
        }
        __syncthreads();

        {
            __half* hh = (__half*)R2;
#pragma unroll
            for (int nt = 0; nt < 4; ++nt) {
                const int col = 16 * nt + lrow;
                const float bv = b2[col];
                const int ch = col >> 3, cl = col & 7;
#pragma unroll
                for (int r = 0; r < 4; ++r) {
                    const int rw = 16 * w + 4 * lq + r;
                    hh[rw * 64 + ((ch ^ (rw & 7)) * 8) + cl] = __float2half(lrelu(acc2[nt][r] + bv));
                }
            }
        }
        __syncthreads();

        f32x4 acc3[3];
#pragma unroll
        for (int nt = 0; nt < 3; ++nt) acc3[nt] = (f32x4){0.f, 0.f, 0.f, 0.f};
        {
            const int ar = 16 * w + lrow;
#pragma unroll
            for (int ks = 0; ks < 2; ++ks) {
                const int kc = 4 * ks + lq;
                const f16x8 af = u4h8(R2[ar * 8 + (kc ^ (ar & 7))]);
#pragma unroll
                for (int nt = 0; nt < 3; ++nt) {
                    const int c = 16 * nt + lrow;
                    const uint4 bu = R1[512 + c * 8 + (kc ^ (c & 7))];
                    acc3[nt] = __builtin_amdgcn_mfma_f32_16x16x32_f16(af, u4h8(bu), acc3[nt], 0, 0, 0);
                }
            }
        }
        __syncthreads();

        // stage p_u rows [64][40] in per-sub LDS, then coalesced uint2 stores (NO rin)
        {
            __half* hh = (__half*)R2;
#pragma unroll
            for (int nt = 0; nt < 3; ++nt) {
                const int col = 16 * nt + lrow;
                if (col < 40) {
#pragma unroll
                    for (int r = 0; r < 4; ++r) {
                        const int rw = 16 * w + 4 * lq + r;
                        hh[rw * 40 + col] = __float2half(acc3[nt][r]);
                    }
                }
            }
            __syncthreads();
            for (int ch = t; ch < 640; ch += 256) {
                const int row = ch / 10;
                const int c = ch - row * 10;
                const int gr = row0 + row;
                if (gr < nN) {
                    uint2 v;
                    __builtin_memcpy(&v, hh + row * 40 + c * 4, 8);
                    *(uint2*)(p + (size_t)gr * PSTRIDE + c * 4) = v;
                }
            }
        }
    }
}

// ---------------- pass B: scan rcv partials over slices (word = 2 nodes per thread) ----------------
__global__ __launch_bounds__(256) void scanp_kernel(
    unsigned* __restrict__ partial,
    int* __restrict__ dr_i,
    float* __restrict__ rin, float* __restrict__ rout,
    int nN, int NR, int NS)
{
    const int gid = blockIdx.x * 256 + threadIdx.x;
    if (gid >= NR * HWORDS) return;
    const int r  = gid >> (RANGE_BITS - 1);
    const int wd = gid & (HWORDS - 1);
    unsigned* prcv = partial + (size_t)(r * NS) * HWORDS + wd;
    unsigned run0 = 0, run1 = 0;
    for (int s = 0; s < NS; ++s) {
        unsigned* p = prcv + (size_t)s * HWORDS;
        const unsigned c = *p;
        *p = run0 | (run1 << 16);
        run0 += c & 0xffffu;
        run1 += c >> 16;
    }
    const unsigned* psnd = partial + (size_t)((NR + r) * NS) * HWORDS + wd;
    unsigned t0 = 0, t1 = 0;
    for (int s = 0; s < NS; ++s) {
        const unsigned c = psnd[(size_t)s * HWORDS];
        t0 += c & 0xffffu;
        t1 += c >> 16;
    }
    const int n0 = (r << RANGE_BITS) + 2 * wd;
    if (n0 < nN) {
        dr_i[n0] = (int)run0;
        rout[n0] = rsqrtf(fmaxf((float)run0, 1.f));
        rin[n0]  = rsqrtf(fmaxf((float)t0, 1.f));
    }
    if (n0 + 1 < nN) {
        dr_i[n0 + 1] = (int)run1;
        rout[n0 + 1] = rsqrtf(fmaxf((float)run1, 1.f));
        rin[n0 + 1]  = rsqrtf(fmaxf((float)t1, 1.f));
    }
}

// ---------------- scan stage 1 ----------------
__global__ __launch_bounds__(256) void scan1_kernel(const int* __restrict__ cnt,
                                                    int* __restrict__ rowptr,
                                                    int* __restrict__ bsums, int n)
{
    __shared__ int sd[256];
    const int t = threadIdx.x;
    const int base = blockIdx.x * 1024 + t * 4;
    int v0 = (base + 0 < n) ? cnt[base + 0] : 0;
    int v1 = (base + 1 < n) ? cnt[base + 1] : 0;
    int v2 = (base + 2 < n) ? cnt[base + 2] : 0;
    int v3 = (base + 3 < n) ? cnt[base + 3] : 0;
    const int p1 = v0, p2 = v0 + v1, p3 = v0 + v1 + v2;
    const int tot = p3 + v3;
    sd[t] = tot;
    __syncthreads();
    for (int off = 1; off < 256; off <<= 1) {
        int y = (t >= off) ? sd[t - off] : 0;
        __syncthreads();
        sd[t] += y;
        __syncthreads();
    }
    const int excl = sd[t] - tot;
    if (base + 0 < n) rowptr[base + 0] = excl;
    if (base + 1 < n) rowptr[base + 1] = excl + p1;
    if (base + 2 < n) rowptr[base + 2] = excl + p2;
    if (base + 3 < n) rowptr[base + 3] = excl + p3;
    if (t == 255) bsums[blockIdx.x] = sd[255];
}

// ---------------- scan stage 2 ----------------
__global__ __launch_bounds__(256) void scan2_kernel(int* __restrict__ bsums, int nb)
{
    __shared__ int sd[256];
    const int t = threadIdx.x;
    const int v = (t < nb) ? bsums[t] : 0;
    sd[t] = v;
    __syncthreads();
    for (int off = 1; off < 256; off <<= 1) {
        int y = (t >= off) ? sd[t - off] : 0;
        __syncthreads();
        sd[t] += y;
        __syncthreads();
    }
    if (t < nb) bsums[t] = sd[t] - v;
}

// ---------------- scan stage 3 ----------------
__global__ __launch_bounds__(256) void scan3_kernel(int* __restrict__ rowptr,
                                                    const int* __restrict__ bsums,
                                                    int n, int nE)
{
    const int gid = blockIdx.x * 256 + threadIdx.x;
    if (gid < n) rowptr[gid] += bsums[gid >> 10];
    if (gid == 0) rowptr[n] = nE;
}

// ---------------- pass C: atomic-free CSR fill (standalone) ----------------
__global__ __launch_bounds__(256) void fill_kernel(
    const int* __restrict__ snd, const int* __restrict__ rcv,
    const unsigned short* __restrict__ pos16, const unsigned* __restrict__ partial,
    const int* __restrict__ rowptr, int* __restrict__ csr_src,
    int nE, int NS)
{
    const int i = blockIdx.x * 256 + threadIdx.x;
    if (i >= nE) return;
    const int rv = rcv[i];
    const int r = rv >> RANGE_BITS;
    const int s = i >> SLICE_BITS;
    const unsigned pw = partial[(size_t)(r * NS + s) * HWORDS + ((rv & (RANGE - 1)) >> 1)];
    const int pref = (int)((pw >> ((rv & 1) << 4)) & 0xffffu);
    const int pos = rowptr[rv] + pref + (int)pos16[i];
    csr_src[pos] = snd[i];
}

// ---------------- agg1: 8 lanes/node, batch 16; p is UNSCALED -> lane 5 gathers rin[src]
// (400-KB rin array is L2-resident; gather is cheap) and shfl-broadcasts to its group.
__global__ __launch_bounds__(256) void agg1_kernel(const __half* __restrict__ p,
                                                   const int* __restrict__ csr_src,
                                                   const int* __restrict__ rowptr,
                                                   const float* __restrict__ rin,
                                                   const float* __restrict__ rout,
                                                   __half* __restrict__ qbuf,
                                                   float* __restrict__ cbuf, int nN)
{
    const int gid = blockIdx.x * 256 + threadIdx.x;
    const int node = gid >> 3;
    const int j = gid & 7;
    if (node >= nN) return;
    const int l = (int)(threadIdx.x & 63);
    const int src5 = (l & ~7) | 5;          // lane 5 of this 8-lane group
    const int beg = rowptr[node], end = rowptr[node + 1];
    const bool isch = (j < 5);
    const bool isr  = (j == 5);
    float a[8];
#pragma unroll
    for (int k = 0; k < 8; ++k) a[k] = 0.f;
    float cs = 0.f;

    for (int e = beg; e < end; e += 16) {
        int s[16];
#pragma unroll
        for (int b = 0; b < 16; ++b) {
            const int idx = e + b;
            s[b] = csr_src[idx < end ? idx : end - 1];
        }
        uint4 u[16];
        if (isch) {
#pragma unroll
            for (int b = 0; b < 16; ++b)
                u[b] = ((const uint4*)(p + (size_t)s[b] * PSTRIDE))[j];
        } else if (isr) {
#pragma unroll
            for (int b = 0; b < 16; ++b)
                u[b].x = __float_as_uint(rin[s[b]]);
        }
#pragma unroll
        for (int b = 0; b < 16; ++b) {
            const float rr = __shfl(__uint_as_float(u[b].x), src5);
            if (e + b < end) {
                if (isch) {
                    float2 f;
                    f = unpack2(u[b].x); a[0] += rr * f.x; a[1] += rr * f.y;
                    f = unpack2(u[b].y); a[2] += rr * f.x; a[3] += rr * f.y;
                    f = unpack2(u[b].z); a[4] += rr * f.x; a[5] += rr * f.y;
                    f = unpack2(u[b].w); a[6] += rr * f.x; a[7] += rr * f.y;
                } else if (isr) {
                    cs += rr;
                }
            }
        }
    }

    if (isch) {
        const float sc = rin[node] * rout[node];
        uint4 o;
        o.x = pack2h(a[0] * sc, a[1] * sc);
        o.y = pack2h(a[2] * sc, a[3] * sc);
        o.z = pack2h(a[4] * sc, a[5] * sc);
        o.w = pack2h(a[6] * sc, a[7] * sc);
        ((uint4*)(qbuf + (size_t)node * PSTRIDE))[j] = o;
    } else if (isr) {
        cbuf[node] = cs * rout[node];
    }
}

// ---------------- agg2 + bias-term + softmax -> out (f32); 8 lanes/node, batch 16, padded rows ----------------
__global__ __launch_bounds__(256) void agg2_kernel(const __half* __restrict__ qbuf,
                                                   const int* __restrict__ csr_src,
                                                   const int* __restrict__ rowptr,
                                                   const float* __restrict__ rout,
                                                   const float* __restrict__ cbuf,
                                                   const float* __restrict__ b3,
                                                   float* __restrict__ out, int nN)
{
    const int gid = blockIdx.x * 256 + threadIdx.x;
    const int node = gid >> 3;
    const int j = gid & 7;
    if (node >= nN) return;
    const int beg = rowptr[node], end = rowptr[node + 1];
    const bool isch = (j < 5);
    float a[8];
#pragma unroll
    for (int k = 0; k < 8; ++k) a[k] = 0.f;

    for (int e = beg; e < end; e += 16) {
        int s[16];
#pragma unroll
        for (int b = 0; b < 16; ++b) {
            const int idx = e + b;
            s[b] = csr_src[idx < end ? idx : end - 1];
        }
        if (isch) {
            uint4 u[16];
#pragma unroll
            for (int b = 0; b < 16; ++b)
                u[b] = ((const uint4*)(qbuf + (size_t)s[b] * PSTRIDE))[j];
#pragma unroll
            for (int b = 0; b < 16; ++b) {
                if (e + b < end) {
                    float2 f;
                    f = unpack2(u[b].x); a[0] += f.x; a[1] += f.y;
                    f = unpack2(u[b].y); a[2] += f.x; a[3] += f.y;
                    f = unpack2(u[b].z); a[4] += f.x; a[5] += f.y;
                    f = unpack2(u[b].w); a[6] += f.x; a[7] += f.y;
                }
            }
        }
    }

    const float ro = rout[node];
    const float c  = cbuf[node];
    float z[8];
    float m = -1e30f, ssum = 0.f;
    if (isch) {
#pragma unroll
        for (int k = 0; k < 8; ++k) {
            z[k] = ro * a[k] + c * b3[j * 8 + k];
            m = fmaxf(m, z[k]);
        }
    }
    m = fmaxf(m, __shfl_xor(m, 1));
    m = fmaxf(m, __shfl_xor(m, 2));
    m = fmaxf(m, __shfl_xor(m, 4));
    if (isch) {
#pragma unroll
        for (int k = 0; k < 8; ++k) { z[k] = __expf(z[k] - m); ssum += z[k]; }
    }
    ssum += __shfl_xor(ssum, 1);
    ssum += __shfl_xor(ssum, 2);
    ssum += __shfl_xor(ssum, 4);
    if (isch) {
        const float inv = 1.f / ssum;
        float4* orow = (float4*)(out + (size_t)node * 40);
        orow[j * 2 + 0] = make_float4(z[0] * inv, z[1] * inv, z[2] * inv, z[3] * inv);
        orow[j * 2 + 1] = make_float4(z[4] * inv, z[5] * inv, z[6] * inv, z[7] * inv);
    }
}

extern "C" void kernel_launch(void* const* d_in, const int* in_sizes, int n_in,
                              void* d_out, int out_size, void* d_ws, size_t ws_size,
                              hipStream_t stream)
{
    const float* nodes = (const float*)d_in[0];
    const int*   snd   = (const int*)d_in[1];
    const int*   rcv   = (const int*)d_in[2];
    const float* W1    = (const float*)d_in[3];
    const float* b1    = (const float*)d_in[4];
    const float* W2    = (const float*)d_in[5];
    const float* b2    = (const float*)d_in[6];
    const float* W3    = (const float*)d_in[7];
    const float* b3    = (const float*)d_in[8];

    const int nN = in_sizes[0] / 128;
    const int nE = in_sizes[1];
    const int NR = (nN + RANGE - 1) >> RANGE_BITS;   // 4 for N=100000
    const int NS = (nE + SLICE - 1) >> SLICE_BITS;   // 25 for E=1.6M
    const int nb1 = (nN + 1023) / 1024;
    const int NB_CNT  = 2 * NR * NS;                 // 200
    const int NB_MLP4 = (nN + 255) / 256;            // 391

    size_t off = 0;
    auto alloc = [&](size_t n) { size_t r = off; off += (n + 3) & ~(size_t)3; return r; };
    int*   dr_i    = (int*)d_ws + alloc(nN);
    int*   rowptr  = (int*)d_ws + alloc(nN + 1);
    int*   bsums   = (int*)d_ws + alloc(256);
    float* rin     = (float*)d_ws + alloc(nN);
    float* rout    = (float*)d_ws + alloc(nN);
    float* cbuf    = (float*)d_ws + alloc(nN);
    int*   csr_src = (int*)d_ws + alloc(nE);
    // layout: {partial + pos16} region; qbuf ALIASES it (dead after fill, qbuf written by agg1).
    // pbuf is DISJOINT (countmlp writes pbuf while count blocks write partial/pos16).
    off = (off + 31) & ~(size_t)31;                              // 128-B align
    const size_t psz = (size_t)2 * NR * NS * HWORDS;             // partial words (13.1 MB)
    const size_t possz = ((size_t)nE + 1) / 2;                   // pos16 words (3.2 MB)
    size_t ubase = off;
    unsigned*       partial = (unsigned*)d_ws + ubase;
    unsigned short* pos16   = (unsigned short*)((unsigned*)d_ws + ubase + psz);
    __half* qbuf = (__half*)((unsigned*)d_ws + ubase);           // nN x PSTRIDE fp16 (aliases partial)
    off = ubase + psz + possz;
    off = (off + 31) & ~(size_t)31;                              // 128-B align
    __half* pbuf = (__half*)((int*)d_ws + off);                  // nN x PSTRIDE fp16 (disjoint)

    countmlp_kernel<<<NB_CNT + NB_MLP4, 1024, 0, stream>>>(
        snd, rcv, partial, pos16, nE, NR, NS, NB_CNT,
        nodes, W1, b1, W2, b2, W3, pbuf, nN);
    scanp_kernel<<<(NR * HWORDS + 255) / 256, 256, 0, stream>>>(partial, dr_i, rin, rout, nN, NR, NS);
    scan1_kernel<<<nb1, 256, 0, stream>>>(dr_i, rowptr, bsums, nN);
    scan2_kernel<<<1, 256, 0, stream>>>(bsums, nb1);
    scan3_kernel<<<(nN + 255) / 256, 256, 0, stream>>>(rowptr, bsums, nN, nE);
    fill_kernel<<<(nE + 255) / 256, 256, 0, stream>>>(snd, rcv, pos16, partial, rowptr, csr_src, nE, NS);
    agg1_kernel<<<((size_t)nN * 8 + 255) / 256, 256, 0, stream>>>(pbuf, csr_src, rowptr, rin, rout, qbuf, cbuf, nN);
    agg2_kernel<<<((size_t)nN * 8 + 255) / 256, 256, 0, stream>>>(qbuf, csr_src, rowptr, rout, cbuf, b3, (float*)d_out, nN);
}

// Round 19
// 150.583 us; speedup vs baseline: 1.0418x; 1.0418x over previous
//
#include <hip/hip_runtime.h>
#include <hip/hip_fp16.h>

#define NEG_SLOPE 0.01f
#define RANGE_BITS 15
#define RANGE (1 << RANGE_BITS)     // 32768 nodes per histogram range (16-bit counters, 64 KB LDS)
#define HWORDS (RANGE / 2)          // 16384 packed uint32 words
#define SLICE_BITS 16
#define SLICE (1 << SLICE_BITS)     // 65536 edges per slice (measured-best)
#define PSTRIDE 64                  // halfs per p/q row (128 B = exactly one cache line)

typedef _Float16 f16x8 __attribute__((ext_vector_type(8)));
typedef float f32x4 __attribute__((ext_vector_type(4)));

__device__ __forceinline__ float lrelu(float x) { return x > 0.f ? x : NEG_SLOPE * x; }

__device__ __forceinline__ unsigned pack2h(float a, float b) {
    __half2 h = __floats2half2_rn(a, b);
    unsigned u; __builtin_memcpy(&u, &h, 4); return u;
}
__device__ __forceinline__ float2 unpack2(unsigned u) {
    __half2 h = *reinterpret_cast<__half2*>(&u);
    return __half22float2(h);
}
__device__ __forceinline__ f16x8 u4h8(uint4 u) {
    f16x8 r; __builtin_memcpy(&r, &u, 16); return r;
}

// ---------------- pass A: per-(array,range,slice) LDS histogram, 16-bit counters, int4 scan ----------------
__global__ __launch_bounds__(1024) void count_kernel(
    const int* __restrict__ snd, const int* __restrict__ rcv,
    unsigned* __restrict__ partial, unsigned short* __restrict__ pos16,
    int nE, int NR, int NS)
{
    __shared__ unsigned hist[HWORDS];    // 2 nodes per word
    const int b = blockIdx.x;
    const int a = b / (NR * NS);
    const int rem = b - a * NR * NS;
    const int r = rem / NS;
    const int s = rem - r * NS;
    const int t = threadIdx.x;
    for (int k = t; k < HWORDS; k += 1024) hist[k] = 0u;
    __syncthreads();
    const int base = r << RANGE_BITS;
    const int lo = s << SLICE_BITS;
    const int hi = min(lo + SLICE, nE);
    const int n4 = (hi - lo) >> 2;
    const int* arr = (a == 0) ? rcv : snd;
    const int4* arr4 = (const int4*)(arr + lo);
    if (a == 0) {
        for (int i4 = t; i4 < n4; i4 += 1024) {
            const int4 v = arr4[i4];
            const int ib = lo + i4 * 4;
            int vv[4] = {v.x, v.y, v.z, v.w};
#pragma unroll
            for (int c = 0; c < 4; ++c) {
                const unsigned d = (unsigned)(vv[c] - base);
                if (d < (unsigned)RANGE) {
                    const unsigned sh = (d & 1u) << 4;
                    const unsigned old = atomicAdd(&hist[d >> 1], 1u << sh);
                    pos16[ib + c] = (unsigned short)((old >> sh) & 0xffffu);
                }
            }
        }
        for (int i = lo + n4 * 4 + t; i < hi; i += 1024) {
            const unsigned d = (unsigned)(arr[i] - base);
            if (d < (unsigned)RANGE) {
                const unsigned sh = (d & 1u) << 4;
                const unsigned old = atomicAdd(&hist[d >> 1], 1u << sh);
                pos16[i] = (unsigned short)((old >> sh) & 0xffffu);
            }
        }
    } else {
        for (int i4 = t; i4 < n4; i4 += 1024) {
            const int4 v = arr4[i4];
            int vv[4] = {v.x, v.y, v.z, v.w};
#pragma unroll
            for (int c = 0; c < 4; ++c) {
                const unsigned d = (unsigned)(vv[c] - base);
                if (d < (unsigned)RANGE) atomicAdd(&hist[d >> 1], 1u << ((d & 1u) << 4));
            }
        }
        for (int i = lo + n4 * 4 + t; i < hi; i += 1024) {
            const unsigned d = (unsigned)(arr[i] - base);
            if (d < (unsigned)RANGE) atomicAdd(&hist[d >> 1], 1u << ((d & 1u) << 4));
        }
    }
    __syncthreads();
    unsigned* dst = partial + (size_t)((a * NR + r) * NS + s) * HWORDS;
    for (int k = t; k < HWORDS; k += 1024) dst[k] = hist[k];
}

// ---------------- pass B: scan rcv partials over slices (word = 2 nodes per thread) ----------------
__global__ __launch_bounds__(256) void scanp_kernel(
    unsigned* __restrict__ partial,
    int* __restrict__ dr_i,
    float* __restrict__ rin, float* __restrict__ rout,
    int nN, int NR, int NS)
{
    const int gid = blockIdx.x * 256 + threadIdx.x;
    if (gid >= NR * HWORDS) return;
    const int r  = gid >> (RANGE_BITS - 1);
    const int wd = gid & (HWORDS - 1);
    unsigned* prcv = partial + (size_t)(r * NS) * HWORDS + wd;
    unsigned run0 = 0, run1 = 0;
    for (int s = 0; s < NS; ++s) {
        unsigned* p = prcv + (size_t)s * HWORDS;
        const unsigned c = *p;
        *p = run0 | (run1 << 16);
        run0 += c & 0xffffu;
        run1 += c >> 16;
    }
    const unsigned* psnd = partial + (size_t)((NR + r) * NS) * HWORDS + wd;
    unsigned t0 = 0, t1 = 0;
    for (int s = 0; s < NS; ++s) {
        const unsigned c = psnd[(size_t)s * HWORDS];
        t0 += c & 0xffffu;
        t1 += c >> 16;
    }
    const int n0 = (r << RANGE_BITS) + 2 * wd;
    if (n0 < nN) {
        dr_i[n0] = (int)run0;
        rout[n0] = rsqrtf(fmaxf((float)run0, 1.f));
        rin[n0]  = rsqrtf(fmaxf((float)t0, 1.f));
    }
    if (n0 + 1 < nN) {
        dr_i[n0 + 1] = (int)run1;
        rout[n0 + 1] = rsqrtf(fmaxf((float)run1, 1.f));
        rin[n0 + 1]  = rsqrtf(fmaxf((float)t1, 1.f));
    }
}

// ---------------- scan stage 1 ----------------
__global__ __launch_bounds__(256) void scan1_kernel(const int* __restrict__ cnt,
                                                    int* __restrict__ rowptr,
                                                    int* __restrict__ bsums, int n)
{
    __shared__ int sd[256];
    const int t = threadIdx.x;
    const int base = blockIdx.x * 1024 + t * 4;
    int v0 = (base + 0 < n) ? cnt[base + 0] : 0;
    int v1 = (base + 1 < n) ? cnt[base + 1] : 0;
    int v2 = (base + 2 < n) ? cnt[base + 2] : 0;
    int v3 = (base + 3 < n) ? cnt[base + 3] : 0;
    const int p1 = v0, p2 = v0 + v1, p3 = v0 + v1 + v2;
    const int tot = p3 + v3;
    sd[t] = tot;
    __syncthreads();
    for (int off = 1; off < 256; off <<= 1) {
        int y = (t >= off) ? sd[t - off] : 0;
        __syncthreads();
        sd[t] += y;
        __syncthreads();
    }
    const int excl = sd[t] - tot;
    if (base + 0 < n) rowptr[base + 0] = excl;
    if (base + 1 < n) rowptr[base + 1] = excl + p1;
    if (base + 2 < n) rowptr[base + 2] = excl + p2;
    if (base + 3 < n) rowptr[base + 3] = excl + p3;
    if (t == 255) bsums[blockIdx.x] = sd[255];
}

// ---------------- scan stage 2 ----------------
__global__ __launch_bounds__(256) void scan2_kernel(int* __restrict__ bsums, int nb)
{
    __shared__ int sd[256];
    const int t = threadIdx.x;
    const int v = (t < nb) ? bsums[t] : 0;
    sd[t] = v;
    __syncthreads();
    for (int off = 1; off < 256; off <<= 1) {
        int y = (t >= off) ? sd[t - off] : 0;
        __syncthreads();
        sd[t] += y;
        __syncthreads();
    }
    if (t < nb) bsums[t] = sd[t] - v;
}

// ---------------- scan stage 3 ----------------
__global__ __launch_bounds__(256) void scan3_kernel(int* __restrict__ rowptr,
                                                    const int* __restrict__ bsums,
                                                    int n, int nE)
{
    const int gid = blockIdx.x * 256 + threadIdx.x;
    if (gid < n) rowptr[gid] += bsums[gid >> 10];
    if (gid == 0) rowptr[n] = nE;
}

// ---------------- FUSED: mlp blocks [0, NB_MLP) + fill blocks [NB_MLP, NB_MLP+NB_FILL) ----------------
__global__ __launch_bounds__(256) void fillmlp_kernel(
    const float* __restrict__ X, const float* __restrict__ W1, const float* __restrict__ b1,
    const float* __restrict__ W2, const float* __restrict__ b2, const float* __restrict__ W3,
    const float* __restrict__ rin, __half* __restrict__ p, int nN, int NB_MLP,
    const int* __restrict__ snd, const int* __restrict__ rcv,
    const unsigned short* __restrict__ pos16, const unsigned* __restrict__ partial,
    const int* __restrict__ rowptr, int* __restrict__ csr_src, int nE, int NS)
{
    __shared__ uint4 R1[1024];
    __shared__ uint4 R2[512];

    const int blk = (int)blockIdx.x;
    if (blk < NB_MLP) {
        // ===================== MLP path =====================
        const int t    = threadIdx.x;
        const int w    = t >> 6;
        const int l    = t & 63;
        const int lrow = l & 15;
        const int lq   = l >> 4;
        const int row0 = blk * 64;

        {
            const int c = l;
            for (int ch = 0; ch < 4; ++ch) {
                const int kc = 4 * w + ch;
                const float* wp = W1 + (kc * 8) * 64 + c;
                uint4 u;
                u.x = pack2h(wp[0],       wp[64]);
                u.y = pack2h(wp[2 * 64],  wp[3 * 64]);
                u.z = pack2h(wp[4 * 64],  wp[5 * 64]);
                u.w = pack2h(wp[6 * 64],  wp[7 * 64]);
                R1[c * 16 + (kc ^ (c & 7))] = u;
            }
        }

        const int grow = row0 + 16 * w + lrow;
        const bool rowok = grow < nN;
        const float* xr = X + (size_t)grow * 128 + lq * 8;

        // preload entire X row slice (8 float4 in flight)
        float4 xa[4], xb[4];
#pragma unroll
        for (int ks = 0; ks < 4; ++ks) {
            xa[ks] = make_float4(0.f, 0.f, 0.f, 0.f);
            xb[ks] = xa[ks];
            if (rowok) {
                xa[ks] = *(const float4*)(xr + 32 * ks);
                xb[ks] = *(const float4*)(xr + 32 * ks + 4);
            }
        }
        __syncthreads();

        f32x4 acc1[4];
#pragma unroll
        for (int nt = 0; nt < 4; ++nt) acc1[nt] = (f32x4){0.f, 0.f, 0.f, 0.f};

#pragma unroll
        for (int ks = 0; ks < 4; ++ks) {
            uint4 au;
            au.x = pack2h(xa[ks].x, xa[ks].y); au.y = pack2h(xa[ks].z, xa[ks].w);
            au.z = pack2h(xb[ks].x, xb[ks].y); au.w = pack2h(xb[ks].z, xb[ks].w);
            const f16x8 af = u4h8(au);
            const int kc = 4 * ks + lq;
#pragma unroll
            for (int nt = 0; nt < 4; ++nt) {
                const int c = 16 * nt + lrow;
                const uint4 bu = R1[c * 16 + (kc ^ (c & 7))];
                acc1[nt] = __builtin_amdgcn_mfma_f32_16x16x32_f16(af, u4h8(bu), acc1[nt], 0, 0, 0);
            }
        }
        __syncthreads();

        {
            __half* hh = (__half*)R2;
#pragma unroll
            for (int nt = 0; nt < 4; ++nt) {
                const int col = 16 * nt + lrow;
                const float bv = b1[col];
                const int ch = col >> 3, cl = col & 7;
#pragma unroll
                for (int r = 0; r < 4; ++r) {
                    const int rw = 16 * w + 4 * lq + r;
                    hh[rw * 64 + ((ch ^ (rw & 7)) * 8) + cl] = __float2half(lrelu(acc1[nt][r] + bv));
                }
            }
            const int c = l;
#pragma unroll
            for (int ch = 0; ch < 2; ++ch) {
                const int kc = 2 * w + ch;
                const float* wp = W2 + (kc * 8) * 64 + c;
                uint4 u;
                u.x = pack2h(wp[0],      wp[64]);
                u.y = pack2h(wp[2 * 64], wp[3 * 64]);
                u.z = pack2h(wp[4 * 64], wp[5 * 64]);
                u.w = pack2h(wp[6 * 64], wp[7 * 64]);
                R1[c * 8 + (kc ^ (c & 7))] = u;
            }
            if (c < 48) {
                const bool cv = c < 40;
#pragma unroll
                for (int ch = 0; ch < 2; ++ch) {
                    const int kc = 2 * w + ch;
                    const float* wp = W3 + (kc * 8) * 40 + c;
                    uint4 u;
                    u.x = pack2h(cv ? wp[0]      : 0.f, cv ? wp[40]     : 0.f);
                    u.y = pack2h(cv ? wp[2 * 40] : 0.f, cv ? wp[3 * 40] : 0.f);
                    u.z = pack2h(cv ? wp[4 * 40] : 0.f, cv ? wp[5 * 40] : 0.f);
                    u.w = pack2h(cv ? wp[6 * 40] : 0.f, cv ? wp[7 * 40] : 0.f);
                    R1[512 + c * 8 + (kc ^ (c & 7))] = u;
                }
            }
        }
        __syncthreads();

        f32x4 acc2[4];
#pragma unroll
        for (int nt = 0; nt < 4; ++nt) acc2[nt] = (f32x4){0.f, 0.f, 0.f, 0.f};
        {
            const int ar = 16 * w + lrow;
#pragma unroll
            for (int ks = 0; ks < 2; ++ks) {
                const int kc = 4 * ks + lq;
                const f16x8 af = u4h8(R2[ar * 8 + (kc ^ (ar & 7))]);
#pragma unroll
                for (int nt = 0; nt < 4; ++nt) {
                    const int c = 16 * nt + lrow;
                    const uint4 bu = R1[c * 8 + (kc ^ (c & 7))];
                    acc2[nt] = __builtin_amdgcn_mfma_f32_16x16x32_f16(af, u4h8(bu), acc2[nt], 0, 0, 0);
                }
            }
        }
        __syncthreads();

        {
            __half* hh = (__half*)R2;
#pragma unroll
            for (int nt = 0; nt < 4; ++nt) {
                const int col = 16 * nt + lrow;
                const float bv = b2[col];
                const int ch = col >> 3, cl = col & 7;
#pragma unroll
                for (int r = 0; r < 4; ++r) {
                    const int rw = 16 * w + 4 * lq + r;
                    hh[rw * 64 + ((ch ^ (rw & 7)) * 8) + cl] = __float2half(lrelu(acc2[nt][r] + bv));
                }
            }
        }
        __syncthreads();

        f32x4 acc3[3];
#pragma unroll
        for (int nt = 0; nt < 3; ++nt) acc3[nt] = (f32x4){0.f, 0.f, 0.f, 0.f};
        {
            const int ar = 16 * w + lrow;
#pragma unroll
            for (int ks = 0; ks < 2; ++ks) {
                const int kc = 4 * ks + lq;
                const f16x8 af = u4h8(R2[ar * 8 + (kc ^ (ar & 7))]);
#pragma unroll
                for (int nt = 0; nt < 3; ++nt) {
                    const int c = 16 * nt + lrow;
                    const uint4 bu = R1[512 + c * 8 + (kc ^ (c & 7))];
                    acc3[nt] = __builtin_amdgcn_mfma_f32_16x16x32_f16(af, u4h8(bu), acc3[nt], 0, 0, 0);
                }
            }
        }
        __syncthreads();   // GEMM3 reads of R2 done — safe to overwrite

        // stage p rows [64][40] in LDS, then coalesced uint2 stores; rin embedded at col 40
        {
            __half* hh = (__half*)R2;
            float rs[4];
#pragma unroll
            for (int r = 0; r < 4; ++r) {
                const int gr = row0 + 16 * w + 4 * lq + r;
                rs[r] = (gr < nN) ? rin[gr] : 0.f;
            }
#pragma unroll
            for (int nt = 0; nt < 3; ++nt) {
                const int col = 16 * nt + lrow;
                if (col < 40) {
#pragma unroll
                    for (int r = 0; r < 4; ++r) {
                        const int rw = 16 * w + 4 * lq + r;
                        hh[rw * 40 + col] = __float2half(acc3[nt][r] * rs[r]);
                    }
                }
            }
            __syncthreads();
            for (int ch = t; ch < 640; ch += 256) {
                const int row = ch / 10;
                const int c = ch - row * 10;
                const int gr = row0 + row;
                if (gr < nN) {
                    uint2 v;
                    __builtin_memcpy(&v, hh + row * 40 + c * 4, 8);
                    *(uint2*)(p + (size_t)gr * PSTRIDE + c * 4) = v;
                }
            }
            // rin[gr] embedded as fp16 at half-offset 40 (chunk 5 low half)
            for (int row = t; row < 64; row += 256) {
                const int gr = row0 + row;
                if (gr < nN)
                    *(unsigned*)(p + (size_t)gr * PSTRIDE + 40) = pack2h(rin[gr], 0.f);
            }
        }
    } else {
        // ===================== FILL path =====================
        const int i = (blk - NB_MLP) * 256 + (int)threadIdx.x;
        if (i >= nE) return;
        const int rv = rcv[i];
        const int r = rv >> RANGE_BITS;
        const int s = i >> SLICE_BITS;
        const unsigned pw = partial[(size_t)(r * NS + s) * HWORDS + ((rv & (RANGE - 1)) >> 1)];
        const int pref = (int)((pw >> ((rv & 1) << 4)) & 0xffffu);
        const int pos = rowptr[rv] + pref + (int)pos16[i];
        csr_src[pos] = snd[i];
    }
}

// ---------------- agg1: 8 lanes/node, batch 16; lane 5 reads embedded rin (same line as payload) ----------------
__global__ __launch_bounds__(256) void agg1_kernel(const __half* __restrict__ p,
                                                   const int* __restrict__ csr_src,
                                                   const int* __restrict__ rowptr,
                                                   const float* __restrict__ rin,
                                                   const float* __restrict__ rout,
                                                   __half* __restrict__ qbuf,
                                                   float* __restrict__ cbuf, int nN)
{
    const int gid = blockIdx.x * 256 + threadIdx.x;
    const int node = gid >> 3;
    const int j = gid & 7;
    if (node >= nN) return;
    const int beg = rowptr[node], end = rowptr[node + 1];
    const bool isch = (j < 5);
    const bool isr  = (j == 5);
    const bool isld = (j < 6);          // lanes 0..5 all load chunk j of the row line
    float a[8];
#pragma unroll
    for (int k = 0; k < 8; ++k) a[k] = 0.f;
    float cs = 0.f;

    for (int e = beg; e < end; e += 16) {
        int s[16];
#pragma unroll
        for (int b = 0; b < 16; ++b) {
            const int idx = e + b;
            s[b] = csr_src[idx < end ? idx : end - 1];
        }
        if (isld) {
            uint4 u[16];
#pragma unroll
            for (int b = 0; b < 16; ++b)
                u[b] = ((const uint4*)(p + (size_t)s[b] * PSTRIDE))[j];
            if (isch) {
#pragma unroll
                for (int b = 0; b < 16; ++b) {
                    if (e + b < end) {
                        float2 f;
                        f = unpack2(u[b].x); a[0] += f.x; a[1] += f.y;
                        f = unpack2(u[b].y); a[2] += f.x; a[3] += f.y;
                        f = unpack2(u[b].z); a[4] += f.x; a[5] += f.y;
                        f = unpack2(u[b].w); a[6] += f.x; a[7] += f.y;
                    }
                }
            } else {
#pragma unroll
                for (int b = 0; b < 16; ++b) {
                    if (e + b < end) cs += unpack2(u[b].x).x;   // embedded rin[src]
                }
            }
        }
    }

    if (isch) {
        const float sc = rin[node] * rout[node];
        uint4 o;
        o.x = pack2h(a[0] * sc, a[1] * sc);
        o.y = pack2h(a[2] * sc, a[3] * sc);
        o.z = pack2h(a[4] * sc, a[5] * sc);
        o.w = pack2h(a[6] * sc, a[7] * sc);
        ((uint4*)(qbuf + (size_t)node * PSTRIDE))[j] = o;
    } else if (isr) {
        cbuf[node] = cs * rout[node];
    }
}

// ---------------- agg2 + bias-term + softmax -> out (f32); 8 lanes/node, batch 16, padded rows ----------------
__global__ __launch_bounds__(256) void agg2_kernel(const __half* __restrict__ qbuf,
                                                   const int* __restrict__ csr_src,
                                                   const int* __restrict__ rowptr,
                                                   const float* __restrict__ rout,
                                                   const float* __restrict__ cbuf,
                                                   const float* __restrict__ b3,
                                                   float* __restrict__ out, int nN)
{
    const int gid = blockIdx.x * 256 + threadIdx.x;
    const int node = gid >> 3;
    const int j = gid & 7;
    if (node >= nN) return;
    const int beg = rowptr[node], end = rowptr[node + 1];
    const bool isch = (j < 5);
    float a[8];
#pragma unroll
    for (int k = 0; k < 8; ++k) a[k] = 0.f;

    for (int e = beg; e < end; e += 16) {
        int s[16];
#pragma unroll
        for (int b = 0; b < 16; ++b) {
            const int idx = e + b;
            s[b] = csr_src[idx < end ? idx : end - 1];
        }
        if (isch) {
            uint4 u[16];
#pragma unroll
            for (int b = 0; b < 16; ++b)
                u[b] = ((const uint4*)(qbuf + (size_t)s[b] * PSTRIDE))[j];
#pragma unroll
            for (int b = 0; b < 16; ++b) {
                if (e + b < end) {
                    float2 f;
                    f = unpack2(u[b].x); a[0] += f.x; a[1] += f.y;
                    f = unpack2(u[b].y); a[2] += f.x; a[3] += f.y;
                    f = unpack2(u[b].z); a[4] += f.x; a[5] += f.y;
                    f = unpack2(u[b].w); a[6] += f.x; a[7] += f.y;
                }
            }
        }
    }

    const float ro = rout[node];
    const float c  = cbuf[node];
    float z[8];
    float m = -1e30f, ssum = 0.f;
    if (isch) {
#pragma unroll
        for (int k = 0; k < 8; ++k) {
            z[k] = ro * a[k] + c * b3[j * 8 + k];
            m = fmaxf(m, z[k]);
        }
    }
    m = fmaxf(m, __shfl_xor(m, 1));
    m = fmaxf(m, __shfl_xor(m, 2));
    m = fmaxf(m, __shfl_xor(m, 4));
    if (isch) {
#pragma unroll
        for (int k = 0; k < 8; ++k) { z[k] = __expf(z[k] - m); ssum += z[k]; }
    }
    ssum += __shfl_xor(ssum, 1);
    ssum += __shfl_xor(ssum, 2);
    ssum += __shfl_xor(ssum, 4);
    if (isch) {
        const float inv = 1.f / ssum;
        float4* orow = (float4*)(out + (size_t)node * 40);
        orow[j * 2 + 0] = make_float4(z[0] * inv, z[1] * inv, z[2] * inv, z[3] * inv);
        orow[j * 2 + 1] = make_float4(z[4] * inv, z[5] * inv, z[6] * inv, z[7] * inv);
    }
}

extern "C" void kernel_launch(void* const* d_in, const int* in_sizes, int n_in,
                              void* d_out, int out_size, void* d_ws, size_t ws_size,
                              hipStream_t stream)
{
    const float* nodes = (const float*)d_in[0];
    const int*   snd   = (const int*)d_in[1];
    const int*   rcv   = (const int*)d_in[2];
    const float* W1    = (const float*)d_in[3];
    const float* b1    = (const float*)d_in[4];
    const float* W2    = (const float*)d_in[5];
    const float* b2    = (const float*)d_in[6];
    const float* W3    = (const float*)d_in[7];
    const float* b3    = (const float*)d_in[8];

    const int nN = in_sizes[0] / 128;
    const int nE = in_sizes[1];
    const int NR = (nN + RANGE - 1) >> RANGE_BITS;   // 4 for N=100000
    const int NS = (nE + SLICE - 1) >> SLICE_BITS;   // 25 for E=1.6M
    const int nb1 = (nN + 1023) / 1024;
    const int NB_MLP  = (nN + 63) / 64;
    const int NB_FILL = (nE + 255) / 256;

    size_t off = 0;
    auto alloc = [&](size_t n) { size_t r = off; off += (n + 3) & ~(size_t)3; return r; };
    int*   dr_i    = (int*)d_ws + alloc(nN);
    int*   rowptr  = (int*)d_ws + alloc(nN + 1);
    int*   bsums   = (int*)d_ws + alloc(256);
    float* rin     = (float*)d_ws + alloc(nN);
    float* rout    = (float*)d_ws + alloc(nN);
    float* cbuf    = (float*)d_ws + alloc(nN);
    int*   csr_src = (int*)d_ws + alloc(nE);
    // layout: {partial + pos16} region; qbuf ALIASES it (dead after fill, qbuf written by agg1).
    // pbuf is DISJOINT (fill reads partial/pos16 concurrently with mlp writing pbuf).
    off = (off + 31) & ~(size_t)31;                              // 128-B align
    const size_t psz = (size_t)2 * NR * NS * HWORDS;             // partial words (13.1 MB)
    const size_t possz = ((size_t)nE + 1) / 2;                   // pos16 words (3.2 MB)
    size_t ubase = off;
    unsigned*       partial = (unsigned*)d_ws + ubase;
    unsigned short* pos16   = (unsigned short*)((unsigned*)d_ws + ubase + psz);
    __half* qbuf = (__half*)((unsigned*)d_ws + ubase);           // nN x PSTRIDE fp16 (12.8 MB, aliases partial)
    off = ubase + psz + possz;
    off = (off + 31) & ~(size_t)31;                              // 128-B align
    __half* pbuf = (__half*)((int*)d_ws + off);                  // nN x PSTRIDE fp16 (12.8 MB, disjoint)

    count_kernel<<<2 * NR * NS, 1024, 0, stream>>>(snd, rcv, partial, pos16, nE, NR, NS);
    scanp_kernel<<<(NR * HWORDS + 255) / 256, 256, 0, stream>>>(partial, dr_i, rin, rout, nN, NR, NS);
    scan1_kernel<<<nb1, 256, 0, stream>>>(dr_i, rowptr, bsums, nN);
    scan2_kernel<<<1, 256, 0, stream>>>(bsums, nb1);
    scan3_kernel<<<(nN + 255) / 256, 256, 0, stream>>>(rowptr, bsums, nN, nE);
    fillmlp_kernel<<<NB_MLP + NB_FILL, 256, 0, stream>>>(
        nodes, W1, b1, W2, b2, W3, rin, pbuf, nN, NB_MLP,
        snd, rcv, pos16, partial, rowptr, csr_src, nE, NS);
    agg1_kernel<<<((size_t)nN * 8 + 255) / 256, 256, 0, stream>>>(pbuf, csr_src, rowptr, rin, rout, qbuf, cbuf, nN);
    agg2_kernel<<<((size_t)nN * 8 + 255) / 256, 256, 0, stream>>>(qbuf, csr_src, rowptr, rout, cbuf, b3, (float*)d_out, nN);
}